// Round 5
// baseline (725.536 us; speedup 1.0000x reference)
//
#include <hip/hip_runtime.h>

#define E_N   8
#define IN_N  4096
#define OUT_N 4096
#define T_N   8192

#define BM 128
#define BN 256
#define BK 64
#define NTHREADS 512

typedef unsigned short u16;
typedef __bf16 bf16_t;
typedef bf16_t bf16x8 __attribute__((ext_vector_type(8)));
typedef u16    u16x8  __attribute__((ext_vector_type(8)));
typedef float  f32x4  __attribute__((ext_vector_type(4)));

// async global->LDS, 16B per lane (dest must be lane-linear: base + lane*16)
#define GLOAD16(gsrc, ldst) \
    __builtin_amdgcn_global_load_lds( \
        (const __attribute__((address_space(1))) unsigned int*)(gsrc), \
        (__attribute__((address_space(3))) unsigned int*)(ldst), 16, 0, 0)

// ---- device-global scratch (ws_size unknown -> module globals) ----
__device__ int g_cnt[E_N];
__device__ int g_base[E_N];
__device__ int g_ids[T_N];
__device__ int g_meta_wide;                       // 1 if meta widened int16->int32
// W in k-block-major tiled layout: element (e, kt, o, kk) at ((e*64+kt)*4096 + o)*64 + kk
__device__ u16 g_W[(long)E_N * OUT_N * IN_N];     // 268 MB dense bf16
__device__ u16 g_xb[(long)T_N * IN_N];            // 67 MB sorted bf16 tokens

__device__ __forceinline__ u16 f2bf(float f) {
    unsigned u = __builtin_bit_cast(unsigned, f);
    u += 0x7FFFu + ((u >> 16) & 1u);              // round-to-nearest-even
    return (u16)(u >> 16);
}

// ---------------- kernel 1: bucket tokens by expert + meta-layout probe ----------------
__global__ void sort_tokens(const int* __restrict__ idx, const u16* __restrict__ meta16) {
    __shared__ int cnt[E_N], off[E_N];
    __shared__ int probe;
    const int tid = threadIdx.x;
    if (tid == 0) probe = 0;
    if (tid < E_N) cnt[tid] = 0;
    __syncthreads();
    // if meta is int32-widened, u16 halves at odd indices are all 0
    if (tid < 64) {
        unsigned v = meta16[2 * (tid * 131072) + 1];   // safe for either layout
        if (v) atomicOr(&probe, 1);
    }
    for (int t = tid; t < T_N; t += blockDim.x) atomicAdd(&cnt[idx[t] & 7], 1);
    __syncthreads();
    if (tid == 0) {
        int s = 0;
        for (int e = 0; e < E_N; ++e) { g_cnt[e] = cnt[e]; g_base[e] = s; off[e] = s; s += cnt[e]; }
        g_meta_wide = (probe == 0) ? 1 : 0;
    }
    __syncthreads();
    for (int t = tid; t < T_N; t += blockDim.x) {
        int p = atomicAdd(&off[idx[t] & 7], 1);
        if (p >= 0 && p < T_N) g_ids[p] = t;
    }
}

// ---------------- kernel 2: gather + convert x (f32) -> sorted bf16 rows ----------------
__global__ __launch_bounds__(256, 4)
void xb_convert(const float* __restrict__ x) {
    const int p = blockIdx.x;                     // sorted row position
    int tok = g_ids[p];
    if ((unsigned)tok >= (unsigned)T_N) tok = 0;
    const float* src = x + (long)tok * IN_N;
    u16* dst = g_xb + (long)p * IN_N;
    const int tid = threadIdx.x;                  // 16 elems per thread
    float va[16];
    #pragma unroll
    for (int c4 = 0; c4 < 4; ++c4) {
        float4 v = *reinterpret_cast<const float4*>(src + tid * 16 + c4 * 4);
        va[c4 * 4 + 0] = v.x; va[c4 * 4 + 1] = v.y; va[c4 * 4 + 2] = v.z; va[c4 * 4 + 3] = v.w;
    }
    unsigned wp[8];
    #pragma unroll
    for (int p8 = 0; p8 < 8; ++p8)
        wp[p8] = (unsigned)f2bf(va[2 * p8]) | ((unsigned)f2bf(va[2 * p8 + 1]) << 16);
    *reinterpret_cast<int4*>(dst + tid * 16)     = make_int4((int)wp[0], (int)wp[1], (int)wp[2], (int)wp[3]);
    *reinterpret_cast<int4*>(dst + tid * 16 + 8) = make_int4((int)wp[4], (int)wp[5], (int)wp[6], (int)wp[7]);
}

// ---------------- kernel 3: decode 2:4 int4 -> dense bf16 W, k-tiled layout ----------------
// grid (OUT/256, 16, E), 256 threads. Thread owns row o, k-range [kt0*256, +256).
__global__ __launch_bounds__(256, 4)
void decode_w(const int* __restrict__ qw, const void* __restrict__ meta) {
    const int e   = blockIdx.z;
    const int kt0 = blockIdx.y * 4;               // 4 k-tiles of 64 -> 16 g-blocks
    const int o   = blockIdx.x * 256 + threadIdx.x;
    const bool mwide = (g_meta_wide != 0);
    // 16 consecutive meta words for g = kt0*4 .. kt0*4+15
    unsigned mws[16];
    if (mwide) {
        const int* mp = (const int*)meta + ((long)e * OUT_N + o) * (IN_N / 16) + kt0 * 4;
        #pragma unroll
        for (int i = 0; i < 16; ++i) mws[i] = (unsigned)mp[i] & 0xFFFFu;
    } else {
        const u16* mp = (const u16*)meta + ((long)e * OUT_N + o) * (IN_N / 16) + kt0 * 4;
        #pragma unroll
        for (int i = 0; i < 16; ++i) mws[i] = mp[i];
    }
    const unsigned sh = (o & 7) << 2;
    #pragma unroll
    for (int ki = 0; ki < 4; ++ki) {
        const int kt = kt0 + ki;
        unsigned wp[32];                          // 64 bf16 = one 128B k-run of row o
        #pragma unroll
        for (int gi = 0; gi < 4; ++gi) {
            const int g = kt * 4 + gi;
            const unsigned mw = mws[ki * 4 + gi];
            const int* qp = qw + ((e * (IN_N / 32) + (g >> 1)) << 13) + (o >> 3) + ((g & 1) << 12);
            int d[16];
            #pragma unroll
            for (int p = 0; p < 16; ++p) d[p] = 0;
            #pragma unroll
            for (int grp = 0; grp < 4; ++grp) {
                const unsigned w0 = (unsigned)qp[(2 * grp) * 512];
                const unsigned w1 = (unsigned)qp[(2 * grp + 1) * 512];
                const int v0 = (int)((w0 >> sh) & 0xF) - 8;
                const int v1 = (int)((w1 >> sh) & 0xF) - 8;
                const int s0 = (mw >> (4 * grp)) & 3;
                const int s1 = (mw >> (4 * grp + 2)) & 3;
                #pragma unroll
                for (int q = 0; q < 4; ++q) {
                    int t0 = (s0 == q) ? v0 : 0;
                    int t1 = (s1 == q) ? v1 : 0;
                    d[grp * 4 + q] = t0 + t1;     // collisions sum, matching .at[].add
                }
            }
            #pragma unroll
            for (int p = 0; p < 8; ++p) {
                unsigned lo = __builtin_bit_cast(unsigned, (float)d[2 * p])     >> 16;  // exact, |d|<=30
                unsigned hi = __builtin_bit_cast(unsigned, (float)d[2 * p + 1]) >> 16;
                wp[gi * 8 + p] = lo | (hi << 16);
            }
        }
        u16* wr = g_W + ((long)(e * 64 + kt) * OUT_N + o) * 64;   // contiguous 128B per thread
        #pragma unroll
        for (int q4 = 0; q4 < 8; ++q4)
            *reinterpret_cast<int4*>(wr + q4 * 8) =
                make_int4((int)wp[q4 * 4], (int)wp[q4 * 4 + 1], (int)wp[q4 * 4 + 2], (int)wp[q4 * 4 + 3]);
    }
}

// ---------------- kernel 4: grouped bf16 GEMM, global_load_lds staging ----------------
__global__ __launch_bounds__(NTHREADS, 1)
void moe_gemm(const float* __restrict__ scales, float* __restrict__ y) {
    const int e = blockIdx.z;
    int cnt = g_cnt[e];
    if (cnt < 0) cnt = 0;
    if (cnt > T_N) cnt = T_N;
    const int m0 = blockIdx.y * BM;
    if (m0 >= cnt) return;
    const int n0 = blockIdx.x * BN;
    int base = g_base[e];
    if (base < 0) base = 0;
    if (base > T_N - cnt) base = T_N - cnt;

    __shared__ __align__(16) u16 As[BM * BK];     // linear: chunk n=(row*8+kc), 16B each
    __shared__ __align__(16) u16 Bs[BN * BK];

    const int tid  = threadIdx.x;
    const int lane = tid & 63;
    const int wm   = (tid >> 6) >> 2;             // 0..1
    const int wn   = (tid >> 6) & 3;              // 0..3

    // A staging: chunks tid and tid+512; row = chunk>>3, kc = chunk&7
    const int r0 = tid >> 3, kc = tid & 7;
    long ar0 = (long)base + m0 + r0;       if (ar0 > T_N - 1) ar0 = T_N - 1;
    long ar1 = (long)base + m0 + 64 + r0;  if (ar1 > T_N - 1) ar1 = T_N - 1;
    const u16* asrc0 = g_xb + ar0 * IN_N + kc * 8;
    const u16* asrc1 = g_xb + ar1 * IN_N + kc * 8;
    u16* adst0 = &As[tid * 8];
    u16* adst1 = &As[(tid + 512) * 8];
    // B staging: slab (e,kt) is contiguous [256][64]; source linear == dest linear
    const u16* bsrc = g_W + ((long)e * 64 * OUT_N + n0) * 64 + tid * 8;

    f32x4 acc[4][4];
    #pragma unroll
    for (int i = 0; i < 4; ++i)
        #pragma unroll
        for (int j = 0; j < 4; ++j) acc[i][j] = (f32x4){0.f, 0.f, 0.f, 0.f};

    for (int k0 = 0; k0 < IN_N; k0 += BK) {
        GLOAD16(asrc0 + k0, adst0);
        GLOAD16(asrc1 + k0, adst1);
        #pragma unroll
        for (int it = 0; it < 4; ++it)
            GLOAD16(bsrc + it * 4096, &Bs[(tid + it * 512) * 8]);
        bsrc += (long)OUT_N * 64;                 // next k-slab
        __syncthreads();                          // drains vmcnt before barrier
        #pragma unroll
        for (int kk = 0; kk < BK; kk += 32) {
            bf16x8 af[4], bfr[4];
            #pragma unroll
            for (int mf = 0; mf < 4; ++mf) {
                const int r = wm * 64 + mf * 16 + (lane & 15);
                u16x8 v = *reinterpret_cast<const u16x8*>(&As[r * 64 + kk + ((lane >> 4) << 3)]);
                af[mf] = __builtin_bit_cast(bf16x8, v);
            }
            #pragma unroll
            for (int nf = 0; nf < 4; ++nf) {
                const int r = wn * 64 + nf * 16 + (lane & 15);
                u16x8 v = *reinterpret_cast<const u16x8*>(&Bs[r * 64 + kk + ((lane >> 4) << 3)]);
                bfr[nf] = __builtin_bit_cast(bf16x8, v);
            }
            #pragma unroll
            for (int mf = 0; mf < 4; ++mf)
                #pragma unroll
                for (int nf = 0; nf < 4; ++nf)
                    acc[mf][nf] = __builtin_amdgcn_mfma_f32_16x16x32_bf16(af[mf], bfr[nf], acc[mf][nf], 0, 0, 0);
        }
        __syncthreads();
    }

    // ---- epilogue: scale per (e,col), f32 store, scatter by token id ----
    const int* toks = g_ids + base;
    float sc[4];
    #pragma unroll
    for (int nf = 0; nf < 4; ++nf)
        sc[nf] = scales[e * OUT_N + n0 + wn * 64 + nf * 16 + (lane & 15)];
    #pragma unroll
    for (int mf = 0; mf < 4; ++mf) {
        #pragma unroll
        for (int r = 0; r < 4; ++r) {
            const int row = m0 + wm * 64 + mf * 16 + ((lane >> 4) << 2) + r;
            if (row >= cnt) continue;
            int tok = toks[row];
            if ((unsigned)tok >= (unsigned)T_N) continue;
            float* yrow = y + (long)tok * OUT_N;
            #pragma unroll
            for (int nf = 0; nf < 4; ++nf) {
                const int col = n0 + wn * 64 + nf * 16 + (lane & 15);
                yrow[col] = acc[mf][nf][r] * sc[nf];
            }
        }
    }
}

extern "C" void kernel_launch(void* const* d_in, const int* in_sizes, int n_in,
                              void* d_out, int out_size, void* d_ws, size_t ws_size,
                              hipStream_t stream) {
    // Route inputs by element-count signature (order-robust):
    //   x: 33554432, indices: 8192, scales: 32768, qweight & meta: 8388608 each (dict order: qw first)
    const float* x      = nullptr;
    const int* indices  = nullptr;
    const int* qw       = nullptr;
    const void* meta    = nullptr;
    const float* scales = nullptr;
    int big_seen = 0;
    for (int i = 0; i < n_in; ++i) {
        long s = in_sizes[i];
        if (s == 33554432L)      x = (const float*)d_in[i];
        else if (s == 8192L)     indices = (const int*)d_in[i];
        else if (s == 32768L)    scales = (const float*)d_in[i];
        else if (s == 8388608L) {
            if (big_seen++ == 0)  qw = (const int*)d_in[i];
            else                  meta = d_in[i];
        }
    }
    if (!x || !indices || !qw || !meta || !scales) return;
    float* y = (float*)d_out;

    hipLaunchKernelGGL(sort_tokens, dim3(1), dim3(1024), 0, stream, indices, (const u16*)meta);
    hipLaunchKernelGGL(xb_convert, dim3(T_N), dim3(256), 0, stream, x);
    hipLaunchKernelGGL(decode_w, dim3(OUT_N / 256, 16, E_N), dim3(256), 0, stream, qw, meta);
    hipLaunchKernelGGL(moe_gemm, dim3(OUT_N / BN, T_N / BM, E_N), dim3(NTHREADS), 0, stream, scales, y);
}

// Round 6
// 653.766 us; speedup vs baseline: 1.1098x; 1.1098x over previous
//
#include <hip/hip_runtime.h>

#define E_N   8
#define IN_N  4096
#define OUT_N 4096
#define T_N   8192

#define BM 128
#define BN 256
#define BK 64
#define NTHREADS 512

typedef unsigned short u16;
typedef __bf16 bf16_t;
typedef bf16_t bf16x8 __attribute__((ext_vector_type(8)));
typedef u16    u16x8  __attribute__((ext_vector_type(8)));
typedef float  f32x4  __attribute__((ext_vector_type(4)));

// async global->LDS, 16B per lane (dest must be lane-linear: base + lane*16)
#define GLOAD16(gsrc, ldst) \
    __builtin_amdgcn_global_load_lds( \
        (const __attribute__((address_space(1))) unsigned int*)(gsrc), \
        (__attribute__((address_space(3))) unsigned int*)(ldst), 16, 0, 0)

// ---- device-global scratch (ws_size unknown -> module globals) ----
__device__ int g_cnt[E_N];
__device__ int g_base[E_N];
__device__ int g_ids[T_N];
__device__ int g_meta_wide;                       // 1 if meta widened int16->int32
// W stored as the LDS-image of each (e,kt) slab [256 rows][8 chunks of 16B],
// with chunk h of row o stored at chunk index o*8 + (h ^ (o&7))  (T2 swizzle).
__device__ u16 g_W[(long)E_N * OUT_N * IN_N];     // 268 MB dense bf16
__device__ u16 g_xb[(long)T_N * IN_N];            // 67 MB sorted bf16 tokens

__device__ __forceinline__ u16 f2bf(float f) {
    unsigned u = __builtin_bit_cast(unsigned, f);
    u += 0x7FFFu + ((u >> 16) & 1u);              // round-to-nearest-even
    return (u16)(u >> 16);
}

// ---------------- kernel 1: bucket tokens by expert + meta-layout probe ----------------
__global__ void sort_tokens(const int* __restrict__ idx, const u16* __restrict__ meta16) {
    __shared__ int cnt[E_N], off[E_N];
    __shared__ int probe;
    const int tid = threadIdx.x;
    const int lane = tid & 63;
    if (tid == 0) probe = 0;
    if (tid < E_N) cnt[tid] = 0;
    __syncthreads();
    // if meta is int32-widened, u16 halves at odd indices are all 0
    if (tid < 64) {
        unsigned v = meta16[2 * (tid * 131072) + 1];   // safe for either layout
        if (v) atomicOr(&probe, 1);
    }
    // wave-aggregated counting: 8 ballots per 64 tokens instead of 64 atomics
    for (int t0 = tid - lane; t0 < T_N; t0 += blockDim.x) {
        const int t = t0 + lane;
        const int my = idx[t] & 7;
        #pragma unroll
        for (int e = 0; e < E_N; ++e) {
            unsigned long long m = __ballot(my == e);
            if (lane == 0 && m) atomicAdd(&cnt[e], __popcll(m));
        }
    }
    __syncthreads();
    if (tid == 0) {
        int s = 0;
        for (int e = 0; e < E_N; ++e) { g_cnt[e] = cnt[e]; g_base[e] = s; off[e] = s; s += cnt[e]; }
        g_meta_wide = (probe == 0) ? 1 : 0;
    }
    __syncthreads();
    // wave-aggregated placement (order within expert is irrelevant)
    for (int t0 = tid - lane; t0 < T_N; t0 += blockDim.x) {
        const int t = t0 + lane;
        const int my = idx[t] & 7;
        #pragma unroll
        for (int e = 0; e < E_N; ++e) {
            unsigned long long m = __ballot(my == e);
            if (my == e) {
                int below = __popcll(m & ((1ull << lane) - 1ull));
                int basep = 0;
                if (below == 0) basep = atomicAdd(&off[e], __popcll(m));
                // broadcast leader's base to the group's lanes
                int src = __ffsll((long long)m) - 1;
                basep = __shfl(basep, src);
                int p = basep + below;
                if (p >= 0 && p < T_N) g_ids[p] = t;
            }
        }
    }
}

// ---------------- kernel 2: gather + convert x (f32) -> sorted bf16 rows ----------------
__global__ __launch_bounds__(256, 4)
void xb_convert(const float* __restrict__ x) {
    const int p = blockIdx.x;                     // sorted row position
    int tok = g_ids[p];
    if ((unsigned)tok >= (unsigned)T_N) tok = 0;
    const float* src = x + (long)tok * IN_N;
    u16* dst = g_xb + (long)p * IN_N;
    const int tid = threadIdx.x;                  // 16 elems per thread
    float va[16];
    #pragma unroll
    for (int c4 = 0; c4 < 4; ++c4) {
        float4 v = *reinterpret_cast<const float4*>(src + tid * 16 + c4 * 4);
        va[c4 * 4 + 0] = v.x; va[c4 * 4 + 1] = v.y; va[c4 * 4 + 2] = v.z; va[c4 * 4 + 3] = v.w;
    }
    unsigned wp[8];
    #pragma unroll
    for (int p8 = 0; p8 < 8; ++p8)
        wp[p8] = (unsigned)f2bf(va[2 * p8]) | ((unsigned)f2bf(va[2 * p8 + 1]) << 16);
    *reinterpret_cast<int4*>(dst + tid * 16)     = make_int4((int)wp[0], (int)wp[1], (int)wp[2], (int)wp[3]);
    *reinterpret_cast<int4*>(dst + tid * 16 + 8) = make_int4((int)wp[4], (int)wp[5], (int)wp[6], (int)wp[7]);
}

// ---------------- kernel 3: decode 2:4 int4 -> dense bf16 W, swizzled k-tiled layout ----------------
// grid (OUT/256, 16, E), 256 threads. Thread owns row o, k-range [kt0*256, +256).
__global__ __launch_bounds__(256, 4)
void decode_w(const int* __restrict__ qw, const void* __restrict__ meta) {
    const int e   = blockIdx.z;
    const int kt0 = blockIdx.y * 4;               // 4 k-tiles of 64 -> 16 g-blocks
    const int o   = blockIdx.x * 256 + threadIdx.x;
    const bool mwide = (g_meta_wide != 0);
    // 16 consecutive meta words for g = kt0*4 .. kt0*4+15
    unsigned mws[16];
    if (mwide) {
        const int* mp = (const int*)meta + ((long)e * OUT_N + o) * (IN_N / 16) + kt0 * 4;
        #pragma unroll
        for (int i = 0; i < 16; ++i) mws[i] = (unsigned)mp[i] & 0xFFFFu;
    } else {
        const u16* mp = (const u16*)meta + ((long)e * OUT_N + o) * (IN_N / 16) + kt0 * 4;
        #pragma unroll
        for (int i = 0; i < 16; ++i) mws[i] = mp[i];
    }
    const unsigned sh = (o & 7) << 2;
    const int osw = o & 7;                        // row phase for T2 swizzle
    #pragma unroll
    for (int ki = 0; ki < 4; ++ki) {
        const int kt = kt0 + ki;
        unsigned wp[32];                          // 64 bf16 = one 128B k-run of row o
        #pragma unroll
        for (int gi = 0; gi < 4; ++gi) {
            const int g = kt * 4 + gi;
            const unsigned mw = mws[ki * 4 + gi];
            const int* qp = qw + ((e * (IN_N / 32) + (g >> 1)) << 13) + (o >> 3) + ((g & 1) << 12);
            int d[16];
            #pragma unroll
            for (int p = 0; p < 16; ++p) d[p] = 0;
            #pragma unroll
            for (int grp = 0; grp < 4; ++grp) {
                const unsigned w0 = (unsigned)qp[(2 * grp) * 512];
                const unsigned w1 = (unsigned)qp[(2 * grp + 1) * 512];
                const int v0 = (int)((w0 >> sh) & 0xF) - 8;
                const int v1 = (int)((w1 >> sh) & 0xF) - 8;
                const int s0 = (mw >> (4 * grp)) & 3;
                const int s1 = (mw >> (4 * grp + 2)) & 3;
                #pragma unroll
                for (int q = 0; q < 4; ++q) {
                    int t0 = (s0 == q) ? v0 : 0;
                    int t1 = (s1 == q) ? v1 : 0;
                    d[grp * 4 + q] = t0 + t1;     // collisions sum, matching .at[].add
                }
            }
            #pragma unroll
            for (int p = 0; p < 8; ++p) {
                unsigned lo = __builtin_bit_cast(unsigned, (float)d[2 * p])     >> 16;  // exact, |d|<=30
                unsigned hi = __builtin_bit_cast(unsigned, (float)d[2 * p + 1]) >> 16;
                wp[gi * 8 + p] = lo | (hi << 16);
            }
        }
        u16* wr = g_W + ((long)(e * 64 + kt) * OUT_N + o) * 64;
        // store chunk h at position h ^ (o&7): slab holds the swizzled LDS image
        #pragma unroll
        for (int h = 0; h < 8; ++h)
            *reinterpret_cast<int4*>(wr + (h ^ osw) * 8) =
                make_int4((int)wp[h * 4], (int)wp[h * 4 + 1], (int)wp[h * 4 + 2], (int)wp[h * 4 + 3]);
    }
}

// ---------------- kernel 4: grouped bf16 GEMM, gload_lds + T2 swizzle ----------------
__global__ __launch_bounds__(NTHREADS, 1)
void moe_gemm(const float* __restrict__ scales, float* __restrict__ y) {
    const int e = blockIdx.z;
    int cnt = g_cnt[e];
    if (cnt < 0) cnt = 0;
    if (cnt > T_N) cnt = T_N;
    const int m0 = blockIdx.y * BM;
    if (m0 >= cnt) return;
    const int n0 = blockIdx.x * BN;
    int base = g_base[e];
    if (base < 0) base = 0;
    if (base > T_N - cnt) base = T_N - cnt;

    __shared__ __align__(16) u16 As[BM * BK];     // swizzled image: chunk(r,h) at r*8 + (h^(r&7))
    __shared__ __align__(16) u16 Bs[BN * BK];

    const int tid  = threadIdx.x;
    const int lane = tid & 63;
    const int wm   = (tid >> 6) >> 2;             // 0..1
    const int wn   = (tid >> 6) & 3;              // 0..3

    // A staging: LDS chunk c=tid (+512) holds data chunk h=(c&7)^(r&7), r=c>>3 (+64)
    const int r0 = tid >> 3;
    const int kc_swz = (tid & 7) ^ (r0 & 7);      // same phase for r0 and r0+64
    long ar0 = (long)base + m0 + r0;       if (ar0 > T_N - 1) ar0 = T_N - 1;
    long ar1 = (long)base + m0 + 64 + r0;  if (ar1 > T_N - 1) ar1 = T_N - 1;
    const u16* asrc0 = g_xb + ar0 * IN_N + kc_swz * 8;
    const u16* asrc1 = g_xb + ar1 * IN_N + kc_swz * 8;
    u16* adst0 = &As[tid * 8];
    u16* adst1 = &As[(tid + 512) * 8];
    // B staging: g_W already holds the swizzled slab image -> linear copy
    const u16* bsrc = g_W + ((long)e * 64 * OUT_N + n0) * 64 + tid * 8;

    f32x4 acc[4][4];
    #pragma unroll
    for (int i = 0; i < 4; ++i)
        #pragma unroll
        for (int j = 0; j < 4; ++j) acc[i][j] = (f32x4){0.f, 0.f, 0.f, 0.f};

    for (int k0 = 0; k0 < IN_N; k0 += BK) {
        GLOAD16(asrc0 + k0, adst0);
        GLOAD16(asrc1 + k0, adst1);
        #pragma unroll
        for (int it = 0; it < 4; ++it)
            GLOAD16(bsrc + it * 4096, &Bs[(tid + it * 512) * 8]);
        bsrc += (long)OUT_N * 64;                 // next k-slab
        __syncthreads();                          // drains vmcnt before barrier
        #pragma unroll
        for (int kk = 0; kk < BK; kk += 32) {
            bf16x8 af[4], bfr[4];
            #pragma unroll
            for (int mf = 0; mf < 4; ++mf) {
                const int r = wm * 64 + mf * 16 + (lane & 15);
                const int h = (kk >> 3) + (lane >> 4);
                u16x8 v = *reinterpret_cast<const u16x8*>(&As[r * 64 + ((h ^ (r & 7)) << 3)]);
                af[mf] = __builtin_bit_cast(bf16x8, v);
            }
            #pragma unroll
            for (int nf = 0; nf < 4; ++nf) {
                const int r = wn * 64 + nf * 16 + (lane & 15);
                const int h = (kk >> 3) + (lane >> 4);
                u16x8 v = *reinterpret_cast<const u16x8*>(&Bs[r * 64 + ((h ^ (r & 7)) << 3)]);
                bfr[nf] = __builtin_bit_cast(bf16x8, v);
            }
            #pragma unroll
            for (int mf = 0; mf < 4; ++mf)
                #pragma unroll
                for (int nf = 0; nf < 4; ++nf)
                    acc[mf][nf] = __builtin_amdgcn_mfma_f32_16x16x32_bf16(af[mf], bfr[nf], acc[mf][nf], 0, 0, 0);
        }
        __syncthreads();
    }

    // ---- epilogue: scale per (e,col), f32 store, scatter by token id ----
    const int* toks = g_ids + base;
    float sc[4];
    #pragma unroll
    for (int nf = 0; nf < 4; ++nf)
        sc[nf] = scales[e * OUT_N + n0 + wn * 64 + nf * 16 + (lane & 15)];
    #pragma unroll
    for (int mf = 0; mf < 4; ++mf) {
        #pragma unroll
        for (int r = 0; r < 4; ++r) {
            const int row = m0 + wm * 64 + mf * 16 + ((lane >> 4) << 2) + r;
            if (row >= cnt) continue;
            int tok = toks[row];
            if ((unsigned)tok >= (unsigned)T_N) continue;
            float* yrow = y + (long)tok * OUT_N;
            #pragma unroll
            for (int nf = 0; nf < 4; ++nf) {
                const int col = n0 + wn * 64 + nf * 16 + (lane & 15);
                yrow[col] = acc[mf][nf][r] * sc[nf];
            }
        }
    }
}

extern "C" void kernel_launch(void* const* d_in, const int* in_sizes, int n_in,
                              void* d_out, int out_size, void* d_ws, size_t ws_size,
                              hipStream_t stream) {
    // Route inputs by element-count signature (order-robust):
    //   x: 33554432, indices: 8192, scales: 32768, qweight & meta: 8388608 each (dict order: qw first)
    const float* x      = nullptr;
    const int* indices  = nullptr;
    const int* qw       = nullptr;
    const void* meta    = nullptr;
    const float* scales = nullptr;
    int big_seen = 0;
    for (int i = 0; i < n_in; ++i) {
        long s = in_sizes[i];
        if (s == 33554432L)      x = (const float*)d_in[i];
        else if (s == 8192L)     indices = (const int*)d_in[i];
        else if (s == 32768L)    scales = (const float*)d_in[i];
        else if (s == 8388608L) {
            if (big_seen++ == 0)  qw = (const int*)d_in[i];
            else                  meta = d_in[i];
        }
    }
    if (!x || !indices || !qw || !meta || !scales) return;
    float* y = (float*)d_out;

    hipLaunchKernelGGL(sort_tokens, dim3(1), dim3(1024), 0, stream, indices, (const u16*)meta);
    hipLaunchKernelGGL(xb_convert, dim3(T_N), dim3(256), 0, stream, x);
    hipLaunchKernelGGL(decode_w, dim3(OUT_N / 256, 16, E_N), dim3(256), 0, stream, qw, meta);
    hipLaunchKernelGGL(moe_gemm, dim3(OUT_N / BN, T_N / BM, E_N), dim3(NTHREADS), 0, stream, scales, y);
}

// Round 7
// 648.054 us; speedup vs baseline: 1.1196x; 1.0088x over previous
//
#include <hip/hip_runtime.h>

#define E_N   8
#define IN_N  4096
#define OUT_N 4096
#define T_N   8192

#define BM 256
#define BN 256
#define NT_K 64            // number of 64-wide K-tiles
#define NTHREADS 512

typedef unsigned short u16;
typedef __bf16 bf16_t;
typedef bf16_t bf16x8 __attribute__((ext_vector_type(8)));
typedef u16    u16x8  __attribute__((ext_vector_type(8)));
typedef float  f32x4  __attribute__((ext_vector_type(4)));

// async global->LDS, 16B per lane (dest must be lane-linear: base + lane*16)
#define GLOAD16(gsrc, ldst) \
    __builtin_amdgcn_global_load_lds( \
        (const __attribute__((address_space(1))) unsigned int*)(gsrc), \
        (__attribute__((address_space(3))) unsigned int*)(ldst), 16, 0, 0)

// ---- device-global scratch (ws_size unknown -> module globals) ----
__device__ int g_cnt[E_N];
__device__ int g_base[E_N];
__device__ int g_ids[T_N];
__device__ int g_meta_wide;                       // 1 if meta widened int16->int32
// W stored as the LDS-image of each (e,kt) slab [256 rows][8 chunks of 16B],
// chunk h of row o at chunk index o*8 + (h ^ (o&7))  (T2 swizzle).
__device__ u16 g_W[(long)E_N * OUT_N * IN_N];     // 268 MB dense bf16
__device__ u16 g_xb[(long)T_N * IN_N];            // 67 MB sorted bf16 tokens

__device__ __forceinline__ u16 f2bf(float f) {
    unsigned u = __builtin_bit_cast(unsigned, f);
    u += 0x7FFFu + ((u >> 16) & 1u);              // round-to-nearest-even
    return (u16)(u >> 16);
}

// ---------------- kernel 1: bucket tokens by expert + meta-layout probe ----------------
__global__ void sort_tokens(const int* __restrict__ idx, const u16* __restrict__ meta16) {
    __shared__ int cnt[E_N], off[E_N];
    __shared__ int probe;
    const int tid = threadIdx.x;
    const int lane = tid & 63;
    if (tid == 0) probe = 0;
    if (tid < E_N) cnt[tid] = 0;
    __syncthreads();
    if (tid < 64) {
        unsigned v = meta16[2 * (tid * 131072) + 1];   // int32-widened meta -> odd u16 halves all 0
        if (v) atomicOr(&probe, 1);
    }
    for (int t0 = tid - lane; t0 < T_N; t0 += blockDim.x) {
        const int t = t0 + lane;
        const int my = idx[t] & 7;
        #pragma unroll
        for (int e = 0; e < E_N; ++e) {
            unsigned long long m = __ballot(my == e);
            if (lane == 0 && m) atomicAdd(&cnt[e], __popcll(m));
        }
    }
    __syncthreads();
    if (tid == 0) {
        int s = 0;
        for (int e = 0; e < E_N; ++e) { g_cnt[e] = cnt[e]; g_base[e] = s; off[e] = s; s += cnt[e]; }
        g_meta_wide = (probe == 0) ? 1 : 0;
    }
    __syncthreads();
    for (int t0 = tid - lane; t0 < T_N; t0 += blockDim.x) {
        const int t = t0 + lane;
        const int my = idx[t] & 7;
        #pragma unroll
        for (int e = 0; e < E_N; ++e) {
            unsigned long long m = __ballot(my == e);
            if (my == e) {
                int below = __popcll(m & ((1ull << lane) - 1ull));
                int basep = 0;
                if (below == 0) basep = atomicAdd(&off[e], __popcll(m));
                int src = __ffsll((long long)m) - 1;
                basep = __shfl(basep, src);
                int p = basep + below;
                if (p >= 0 && p < T_N) g_ids[p] = t;
            }
        }
    }
}

// ---------------- kernel 2: gather + convert x (f32) -> sorted bf16 rows ----------------
__global__ __launch_bounds__(256, 4)
void xb_convert(const float* __restrict__ x) {
    const int p = blockIdx.x;
    int tok = g_ids[p];
    if ((unsigned)tok >= (unsigned)T_N) tok = 0;
    const float* src = x + (long)tok * IN_N;
    u16* dst = g_xb + (long)p * IN_N;
    const int tid = threadIdx.x;
    float va[16];
    #pragma unroll
    for (int c4 = 0; c4 < 4; ++c4) {
        float4 v = *reinterpret_cast<const float4*>(src + tid * 16 + c4 * 4);
        va[c4 * 4 + 0] = v.x; va[c4 * 4 + 1] = v.y; va[c4 * 4 + 2] = v.z; va[c4 * 4 + 3] = v.w;
    }
    unsigned wp[8];
    #pragma unroll
    for (int p8 = 0; p8 < 8; ++p8)
        wp[p8] = (unsigned)f2bf(va[2 * p8]) | ((unsigned)f2bf(va[2 * p8 + 1]) << 16);
    *reinterpret_cast<int4*>(dst + tid * 16)     = make_int4((int)wp[0], (int)wp[1], (int)wp[2], (int)wp[3]);
    *reinterpret_cast<int4*>(dst + tid * 16 + 8) = make_int4((int)wp[4], (int)wp[5], (int)wp[6], (int)wp[7]);
}

// ---------------- kernel 3: decode 2:4 int4 -> dense bf16 W, swizzled k-tiled layout ----------------
__global__ __launch_bounds__(256, 4)
void decode_w(const int* __restrict__ qw, const void* __restrict__ meta) {
    const int e   = blockIdx.z;
    const int kt0 = blockIdx.y * 4;
    const int o   = blockIdx.x * 256 + threadIdx.x;
    const bool mwide = (g_meta_wide != 0);
    unsigned mws[16];
    if (mwide) {
        const int* mp = (const int*)meta + ((long)e * OUT_N + o) * (IN_N / 16) + kt0 * 4;
        #pragma unroll
        for (int i = 0; i < 16; ++i) mws[i] = (unsigned)mp[i] & 0xFFFFu;
    } else {
        const u16* mp = (const u16*)meta + ((long)e * OUT_N + o) * (IN_N / 16) + kt0 * 4;
        #pragma unroll
        for (int i = 0; i < 16; ++i) mws[i] = mp[i];
    }
    const unsigned sh = (o & 7) << 2;
    const int osw = o & 7;
    #pragma unroll
    for (int ki = 0; ki < 4; ++ki) {
        const int kt = kt0 + ki;
        unsigned wp[32];
        #pragma unroll
        for (int gi = 0; gi < 4; ++gi) {
            const int g = kt * 4 + gi;
            const unsigned mw = mws[ki * 4 + gi];
            const int* qp = qw + ((e * (IN_N / 32) + (g >> 1)) << 13) + (o >> 3) + ((g & 1) << 12);
            int d[16];
            #pragma unroll
            for (int p = 0; p < 16; ++p) d[p] = 0;
            #pragma unroll
            for (int grp = 0; grp < 4; ++grp) {
                const unsigned w0 = (unsigned)qp[(2 * grp) * 512];
                const unsigned w1 = (unsigned)qp[(2 * grp + 1) * 512];
                const int v0 = (int)((w0 >> sh) & 0xF) - 8;
                const int v1 = (int)((w1 >> sh) & 0xF) - 8;
                const int s0 = (mw >> (4 * grp)) & 3;
                const int s1 = (mw >> (4 * grp + 2)) & 3;
                #pragma unroll
                for (int q = 0; q < 4; ++q) {
                    int t0 = (s0 == q) ? v0 : 0;
                    int t1 = (s1 == q) ? v1 : 0;
                    d[grp * 4 + q] = t0 + t1;     // collisions sum, matching .at[].add
                }
            }
            #pragma unroll
            for (int p = 0; p < 8; ++p) {
                unsigned lo = __builtin_bit_cast(unsigned, (float)d[2 * p])     >> 16;  // exact, |d|<=30
                unsigned hi = __builtin_bit_cast(unsigned, (float)d[2 * p + 1]) >> 16;
                wp[gi * 8 + p] = lo | (hi << 16);
            }
        }
        u16* wr = g_W + ((long)(e * 64 + kt) * OUT_N + o) * 64;
        #pragma unroll
        for (int h = 0; h < 8; ++h)
            *reinterpret_cast<int4*>(wr + (h ^ osw) * 8) =
                make_int4((int)wp[h * 4], (int)wp[h * 4 + 1], (int)wp[h * 4 + 2], (int)wp[h * 4 + 3]);
    }
}

// ---------------- kernel 4: grouped bf16 GEMM, 256x256 8-phase (T2+T3+T4+T5) ----------------
__global__ __launch_bounds__(NTHREADS, 2)
void moe_gemm(const float* __restrict__ scales, float* __restrict__ y) {
    const int e = blockIdx.z;
    int cnt = g_cnt[e];
    if (cnt < 0) cnt = 0;
    if (cnt > T_N) cnt = T_N;
    const int m0 = blockIdx.y * BM;
    if (m0 >= cnt) return;
    const int n0 = blockIdx.x * BN;
    int base = g_base[e];
    if (base < 0) base = 0;
    if (base > T_N - cnt) base = T_N - cnt;

    __shared__ __align__(16) u16 As[2 * BM * 64];   // 64 KiB, swizzled image
    __shared__ __align__(16) u16 Bs[2 * BN * 64];   // 64 KiB

    const int tid  = threadIdx.x;
    const int lane = tid & 63;
    const int wid  = tid >> 6;
    const int wm   = wid >> 2;     // 0..1
    const int wn   = wid & 3;      // 0..3

    // ---- staging precompute (per-lane swizzled global source, linear LDS dest) ----
    const int r_loc = tid >> 3;
    const int h_a   = (tid & 7) ^ (r_loc & 7);
    const u16* asrc[4];
    #pragma unroll
    for (int q = 0; q < 4; ++q) {                  // q = ht*2 + j : row = m0 + q*64 + r_loc
        long grow = (long)base + m0 + q * 64 + r_loc;
        if (grow > T_N - 1) grow = T_N - 1;        // tail rows: dup data, masked at store
        asrc[q] = g_xb + grow * IN_N + h_a * 8;
    }
    const u16* bsrc = g_W + ((long)e * NT_K * OUT_N + n0) * 64 + (long)tid * 8;

#define STAGE_A(B_, KT_, HT_) do { \
    const int ktc_ = ((KT_) < NT_K) ? (KT_) : (NT_K - 1); \
    GLOAD16(asrc[(HT_)*2 + 0] + ktc_ * 64, &As[(B_)*16384 + ((HT_)*1024 + tid) * 8]); \
    GLOAD16(asrc[(HT_)*2 + 1] + ktc_ * 64, &As[(B_)*16384 + ((HT_)*1024 + 512 + tid) * 8]); \
} while (0)
#define STAGE_B(B_, KT_, HT_) do { \
    const int ktc_ = ((KT_) < NT_K) ? (KT_) : (NT_K - 1); \
    const u16* s_ = bsrc + (long)ktc_ * (OUT_N * 64) + (HT_) * 8192; \
    GLOAD16(s_,        &Bs[(B_)*16384 + ((HT_)*1024 + tid) * 8]); \
    GLOAD16(s_ + 4096, &Bs[(B_)*16384 + ((HT_)*1024 + 512 + tid) * 8]); \
} while (0)

    // ---- MFMA-read precompute ----
    const int l15   = lane & 15;
    const int aoff0 = ((((lane >> 4))     ^ (lane & 7)) << 3);   // ks=0: h = lane>>4
    const int aoff1 = (((4 + (lane >> 4)) ^ (lane & 7)) << 3);   // ks=1: h = 4 + lane>>4
    const int arow0 = (wm * 128 + l15) * 64;
    const int brow0 = (wn * 64  + l15) * 64;

#define LD8(P_) __builtin_bit_cast(bf16x8, *reinterpret_cast<const u16x8*>(P_))
#define VM4 asm volatile("s_waitcnt vmcnt(4)" ::: "memory")
#define PH_NOP ((void)0)

    f32x4 acc[8][4];
    #pragma unroll
    for (int i = 0; i < 8; ++i)
        #pragma unroll
        for (int j = 0; j < 4; ++j) acc[i][j] = (f32x4){0.f, 0.f, 0.f, 0.f};

    bf16x8 aR[4][2];       // A frags for current qm (reused across 2 phases)
    bf16x8 bR[2][2][2];    // B frags for BOTH qn (B LDS region free after phase 2)

// one phase: {ds_read subtile | stage 1 half-tile | barrier | lgkmcnt(0) | setprio(1) 16xMFMA setprio(0) | tail | barrier}
#define PH(B_, QM_, QN_, RDA_, RDB_, STAGE_STMT, TAIL_STMT) do { \
    if (RDA_) { _Pragma("unroll") for (int mf = 0; mf < 4; ++mf) { \
        const u16* p_ = &As[(B_)*16384 + arow0 + (QM_)*4096 + mf*1024]; \
        aR[mf][0] = LD8(p_ + aoff0); aR[mf][1] = LD8(p_ + aoff1); } } \
    if (RDB_) { _Pragma("unroll") for (int nf = 0; nf < 2; ++nf) { \
        const u16* p_ = &Bs[(B_)*16384 + brow0 + (QN_)*2048 + nf*1024]; \
        bR[QN_][nf][0] = LD8(p_ + aoff0); bR[QN_][nf][1] = LD8(p_ + aoff1); } } \
    STAGE_STMT; \
    __builtin_amdgcn_s_barrier(); \
    asm volatile("s_waitcnt lgkmcnt(0)" ::: "memory"); \
    __builtin_amdgcn_sched_barrier(0); \
    __builtin_amdgcn_s_setprio(1); \
    _Pragma("unroll") for (int ks = 0; ks < 2; ++ks) \
      _Pragma("unroll") for (int mf = 0; mf < 4; ++mf) \
        _Pragma("unroll") for (int nf = 0; nf < 2; ++nf) \
          acc[(QM_)*4 + mf][(QN_)*2 + nf] = __builtin_amdgcn_mfma_f32_16x16x32_bf16( \
              aR[mf][ks], bR[QN_][nf][ks], acc[(QM_)*4 + mf][(QN_)*2 + nf], 0, 0, 0); \
    __builtin_amdgcn_s_setprio(0); \
    TAIL_STMT; \
    __builtin_amdgcn_s_barrier(); \
} while (0)

    // prologue: A(0),B(0) -> buf0; B(1) -> buf1; allow B(1) in flight
    STAGE_A(0, 0, 0); STAGE_A(0, 0, 1);
    STAGE_B(0, 0, 0); STAGE_B(0, 0, 1);
    STAGE_B(1, 1, 0); STAGE_B(1, 1, 1);
    VM4;
    __builtin_amdgcn_s_barrier();

    for (int t = 0; t < NT_K / 2; ++t) {
        const int k1 = 2 * t + 1, k2 = 2 * t + 2, k3 = 2 * t + 3;
        PH(0, 0, 0, 1, 1, STAGE_A(1, k1, 0), PH_NOP);   // buf1 A free since prev ph7
        PH(0, 0, 1, 0, 1, STAGE_A(1, k1, 1), PH_NOP);
        PH(0, 1, 0, 1, 0, STAGE_B(0, k2, 0), PH_NOP);   // buf0 B free after ph2
        PH(0, 1, 1, 0, 0, STAGE_B(0, k2, 1), VM4);      // A(k1) landed before ph5
        PH(1, 0, 0, 1, 1, STAGE_A(0, k2, 0), PH_NOP);   // buf0 A free after ph3
        PH(1, 0, 1, 0, 1, STAGE_A(0, k2, 1), PH_NOP);
        PH(1, 1, 0, 1, 0, STAGE_B(1, k3, 0), PH_NOP);   // buf1 B free after ph6
        PH(1, 1, 1, 0, 0, STAGE_B(1, k3, 1), VM4);      // A(k2),B(k2) landed before next ph1
    }

    // ---- epilogue: scale per (e,col), f32 store, scatter by token id ----
    const int* toks = g_ids + base;
    float sc[4];
    #pragma unroll
    for (int nf = 0; nf < 4; ++nf)
        sc[nf] = scales[e * OUT_N + n0 + wn * 64 + nf * 16 + l15];
    #pragma unroll
    for (int mf = 0; mf < 8; ++mf) {
        #pragma unroll
        for (int r = 0; r < 4; ++r) {
            const int row = m0 + wm * 128 + mf * 16 + ((lane >> 4) << 2) + r;
            if (row >= cnt) continue;
            int tok = toks[row];
            if ((unsigned)tok >= (unsigned)T_N) continue;
            float* yrow = y + (long)tok * OUT_N;
            #pragma unroll
            for (int nf = 0; nf < 4; ++nf)
                yrow[n0 + wn * 64 + nf * 16 + l15] = acc[mf][nf][r] * sc[nf];
        }
    }
}

extern "C" void kernel_launch(void* const* d_in, const int* in_sizes, int n_in,
                              void* d_out, int out_size, void* d_ws, size_t ws_size,
                              hipStream_t stream) {
    const float* x      = nullptr;
    const int* indices  = nullptr;
    const int* qw       = nullptr;
    const void* meta    = nullptr;
    const float* scales = nullptr;
    int big_seen = 0;
    for (int i = 0; i < n_in; ++i) {
        long s = in_sizes[i];
        if (s == 33554432L)      x = (const float*)d_in[i];
        else if (s == 8192L)     indices = (const int*)d_in[i];
        else if (s == 32768L)    scales = (const float*)d_in[i];
        else if (s == 8388608L) {
            if (big_seen++ == 0)  qw = (const int*)d_in[i];
            else                  meta = d_in[i];
        }
    }
    if (!x || !indices || !qw || !meta || !scales) return;
    float* y = (float*)d_out;

    hipLaunchKernelGGL(sort_tokens, dim3(1), dim3(1024), 0, stream, indices, (const u16*)meta);
    hipLaunchKernelGGL(xb_convert, dim3(T_N), dim3(256), 0, stream, x);
    hipLaunchKernelGGL(decode_w, dim3(OUT_N / 256, 16, E_N), dim3(256), 0, stream, qw, meta);
    hipLaunchKernelGGL(moe_gemm, dim3(OUT_N / BN, T_N / BM, E_N), dim3(NTHREADS), 0, stream, scales, y);
}